// Round 4
// baseline (2855.139 us; speedup 1.0000x reference)
//
#include <hip/hip_runtime.h>
#include <stdint.h>

// ---------------------------------------------------------------------------
// BasicLSTM on MI355X — persistent pipelined 2-layer LSTM, round 9.
//
// Structure: 256 WGs x 256 threads, 1 block/CU (launch_bounds 256,1).
// 8 batch groups x 16 rows; per group 32 WGs (2 layers x 16 col-slices).
// Weights live in registers (MFMA B-frags) for all 513 epochs.
//
// ROUND-9: PROTOCOL-IDENTICAL to the verified round-5 kernel (2855 us,
// passed). Rounds 6-8 failed blind (2x hang-like, 1x container error);
// this round deliberately keeps the round-5 inter-WG protocol byte-for-
// byte (monolithic 32-tag gate, relaxed system-scope atomics, same
// publish/barrier structure) and changes ONLY WG-local scheduling:
//  * L0's x-half (KT 0..7, W_ih*x_t) depends on nothing inter-WG ->
//    stage x(s) + run its 16 MFMAs BEFORE the gate (one extra barrier
//    separates x-stage writes from x-MFMA reads).
//  * x(s+1) prefetched into registers right after staging x(s): HBM
//    latency hides under the entire epoch instead of the pre-gate window.
//  * This removes x-stage cvt + 8 MFMA pairs (~400-600 cy) from L0's
//    post-gate critical cycle (the global dependency loop).
// L1 path, gate, h staging, h-half MFMAs, nonlinearity, h store, publish:
// unchanged from round 5. Safety: gate still waits all 32 tags >= s
// before ANY h-slot access; x-MFMA reads (At bytes 0..511) disjoint from
// h-stage writes (bytes 512+), additionally ordered by the gate barrier;
// end-of-epoch barrier orders epoch-s At reads before epoch-s+1 x writes.
// ---------------------------------------------------------------------------

using s16x8 = __attribute__((ext_vector_type(8))) short;   // 8 bf16 = 4 VGPRs
using f32x4 = __attribute__((ext_vector_type(4))) float;
typedef unsigned long long ull;

#define WSB1_OFF 1572864     // L0 frags: 16*8*24*512 = 1572864 ushorts
#define HB0_OFF  3670016     // h0 slots: 2*128*512 = 131072
#define HB1_OFF  3801088     // h1 slots: 131072 (end 3932160)
#define TAGS_BYTE_OFF 7864320  // 256 tags * 128 B = 32 KB

__device__ __forceinline__ float bf2f(unsigned short u) {
    unsigned v = ((unsigned)u) << 16;
    return __builtin_bit_cast(float, v);
}
__device__ __forceinline__ unsigned short f2bf(float f) {
    unsigned x = __builtin_bit_cast(unsigned, f);
    x += 0x7FFFu + ((x >> 16) & 1u);          // RNE (finite values only)
    return (unsigned short)(x >> 16);
}
__device__ __forceinline__ float sigm(float x) { return 1.f / (1.f + __expf(-x)); }
__device__ __forceinline__ float tanhc(float x) {
    x = fminf(15.f, fmaxf(-15.f, x));
    float e = __expf(-2.f * x);
    return (1.f - e) / (1.f + e);
}

// ---------------------------------------------------------------------------
// Prep: weights fp32 -> bf16 MFMA B-frags in packed-gate layout; zero the
// h slots that epoch-0/1 consumers read as "h(-1)"; zero tags.
// Packed layout: slice rt, wave w owns hidden cols j = w*8..w*8+7;
//   tile (w,0) cols = [i(j0..7) | f(j0..7)], tile (w,1) = [g(j0..7) | o(j0..7)].
// ---------------------------------------------------------------------------
__device__ __forceinline__ void store_frag(unsigned short* dst, int n, int kc, int KT,
                                           const float* src) {
    s16x8 v;
#pragma unroll
    for (int e = 0; e < 8; ++e) v[e] = (short)f2bf(src[e]);
    int gate = n >> 9, hid = n & 511;
    int rt = hid >> 5;
    int w  = (hid >> 3) & 3;
    int t  = gate >> 1;
    int lo = (gate & 1) * 8 + (hid & 7);
    int tileIdx = w * 2 + t;
    int kt = kc >> 2, q = kc & 3;
    int lane = q * 16 + lo;
    size_t off = ((((size_t)rt * 8 + tileIdx) * KT + kt) * 64 + lane) * 8;
    *(s16x8*)(dst + off) = v;
}

__global__ void k_prep(const float* __restrict__ wih0, const float* __restrict__ whh0,
                       const float* __restrict__ wih1, const float* __restrict__ whh1,
                       unsigned short* __restrict__ wsB0, unsigned short* __restrict__ wsB1,
                       unsigned short* __restrict__ hb0, unsigned short* __restrict__ hb1,
                       unsigned* __restrict__ tags) {
    int idx = blockIdx.x * 256 + threadIdx.x;
    if (idx < 196608) {                       // L0: 2048 rows x 96 k-chunks
        int n = idx / 96, kc = idx - n * 96;
        int k = kc * 8;
        const float* src = (k < 256) ? (wih0 + (size_t)n * 256 + k)
                                     : (whh0 + (size_t)n * 512 + (k - 256));
        store_frag(wsB0, n, kc, 24, src);
    } else if (idx < 458752) {                // L1: 2048 rows x 128 k-chunks
        int j = idx - 196608;
        int n = j >> 7, kc = j & 127;
        int k = kc * 8;
        const float* src = (k < 512) ? (wih1 + (size_t)n * 512 + k)
                                     : (whh1 + (size_t)n * 512 + (k - 512));
        store_frag(wsB1, n, kc, 32, src);
    } else {
        int z = idx - 458752;
        if (z < 8192) {                       // zero hb0 slot 1 (h0(-1))
            ull* p = (ull*)(hb0 + 65536 + (size_t)z * 8);
            p[0] = 0ull; p[1] = 0ull;
        } else if (z < 16384) {               // zero hb1 slot 0 (h1(-1))
            ull* p = (ull*)(hb1 + (size_t)(z - 8192) * 8);
            p[0] = 0ull; p[1] = 0ull;
        } else if (z < 16640) {               // zero 256 tag words (128-B spaced)
            tags[(size_t)(z - 16384) * 32] = 0u;
        }
    }
}

// ---------------------------------------------------------------------------
// Persistent LSTM kernel
// ---------------------------------------------------------------------------
template <int LAYER, int KT>
__device__ __forceinline__ void run_layer(const float* __restrict__ x,
                                          const unsigned short* __restrict__ wsB,
                                          unsigned short* hsrc0,   // L0: hb0 ; L1: hb0 (y0)
                                          unsigned short* hself,   // write target (hb0/hb1)
                                          unsigned* tags,          // group tag base (32 tags)
                                          unsigned* mytag,
                                          float bv0, float bv1,
                                          int g, int rt, int w, int lane, int tid,
                                          char* At) {
    constexpr int PITCH = (LAYER == 0) ? 1600 : 2112;   // bytes/row, ==64 mod 128
    constexpr int KTX   = 8;                            // L0 x-half KT count
    const int lm = lane & 15, lq = lane >> 4;

    // --- weight fragments into registers/AGPRs (live across all epochs) ---
    s16x8 bfr0[KT], bfr1[KT];
    {
        const unsigned short* base = wsB + (((size_t)rt * 8 + 2 * w) * KT) * 512;
#pragma unroll
        for (int kt = 0; kt < KT; ++kt) {
            bfr0[kt] = *(const s16x8*)(base + ((size_t)kt * 64 + lane) * 8);
            bfr1[kt] = *(const s16x8*)(base + (((size_t)KT + kt) * 64 + lane) * 8);
        }
    }

    float cst[4] = {0.f, 0.f, 0.f, 0.f};      // cell state: (b=lq*4+r, j=w*8+(lm&7))

    // --- x prefetch state (L0 only): x(0) preloaded before the loop ---
    f32x4 xa[2], xb[2];
    int xrow[2], xch[2];
    if (LAYER == 0) {
#pragma unroll
        for (int i = 0; i < 2; ++i) {
            int task = tid + i * 256;         // 16 rows x 32 chunks (8 fp32 each)
            xrow[i] = task >> 5; xch[i] = task & 31;
            const float* src = x + ((size_t)(g * 16 + xrow[i]) * 512) * 256 + xch[i] * 8;
            xa[i] = *(const f32x4*)(src);
            xb[i] = *(const f32x4*)(src + 4);
        }
    }

#pragma unroll 1
    for (int s = 0; s <= 512; ++s) {
        const bool active = LAYER ? (s >= 1) : (s < 512);
        const int pr = (s + 1) & 1;           // read slot
        const int pw = s & 1;                 // write slot

        f32x4 acc0 = {0.f, 0.f, 0.f, 0.f}, acc1 = {0.f, 0.f, 0.f, 0.f};
        const char* ap = At + lm * PITCH + lq * 16;

        // ---- L0 pre-gate phase: stage x(s), prefetch x(s+1), x-half MFMA ----
        if (LAYER == 0 && active) {
#pragma unroll
            for (int i = 0; i < 2; ++i) {     // x part: cvt + store to LDS
                s16x8 v;
#pragma unroll
                for (int e = 0; e < 4; ++e) { v[e] = (short)f2bf(xa[i][e]); v[4 + e] = (short)f2bf(xb[i][e]); }
                *(s16x8*)(At + xrow[i] * PITCH + xch[i] * 16) = v;
            }
            if (s + 1 < 512) {                // prefetch x(s+1): hides under epoch
#pragma unroll
                for (int i = 0; i < 2; ++i) {
                    const float* src = x + ((size_t)(g * 16 + xrow[i]) * 512 + (s + 1)) * 256 + xch[i] * 8;
                    xa[i] = *(const f32x4*)(src);
                    xb[i] = *(const f32x4*)(src + 4);
                }
            }
            __syncthreads();                  // (A) x staged

#pragma unroll
            for (int kt = 0; kt < KTX; ++kt) {    // x-half MFMAs (no inter-WG dep)
                s16x8 a = *(const s16x8*)(ap + kt * 64);
                acc0 = __builtin_amdgcn_mfma_f32_16x16x32_bf16(a, bfr0[kt], acc0, 0, 0, 0);
                acc1 = __builtin_amdgcn_mfma_f32_16x16x32_bf16(a, bfr1[kt], acc1, 0, 0, 0);
            }
        }

        // ---- gate: all 32 group tags >= s (round-5 protocol, unchanged) ----
        if (tid < 32) {
            unsigned* tp = tags + (size_t)tid * 32;
            while (__hip_atomic_load(tp, __ATOMIC_RELAXED, __HIP_MEMORY_SCOPE_SYSTEM) < (unsigned)s)
                __builtin_amdgcn_s_sleep(1);
        }
        __syncthreads();                      // (B)

        if (active) {
            // ---- stage h tile into LDS (post-gate, round-5 exact) ----
            if (LAYER == 0) {
#pragma unroll
                for (int i = 0; i < 4; ++i) {  // h part: 16 rows x 64 chunks (16 B)
                    int task = tid + i * 256;
                    int row = task >> 6, c8 = task & 63;
                    const ull* sp = (const ull*)(hsrc0 + (size_t)(pr * 128 + g * 16 + row) * 512 + c8 * 8);
                    ull v0 = __hip_atomic_load(sp,     __ATOMIC_RELAXED, __HIP_MEMORY_SCOPE_SYSTEM);
                    ull v1 = __hip_atomic_load(sp + 1, __ATOMIC_RELAXED, __HIP_MEMORY_SCOPE_SYSTEM);
                    ull* d = (ull*)(At + row * PITCH + 512 + c8 * 16);
                    d[0] = v0; d[1] = v1;
                }
            } else {
#pragma unroll
                for (int i = 0; i < 8; ++i) {  // 16 rows x 128 chunks (16 B)
                    int task = tid + i * 256;
                    int row = task >> 7, c8 = task & 127;
                    const unsigned short* sp = (c8 < 64)
                        ? (hsrc0 + (size_t)(pr * 128 + g * 16 + row) * 512 + c8 * 8)
                        : (hself + (size_t)(pr * 128 + g * 16 + row) * 512 + (c8 - 64) * 8);
                    ull v0 = __hip_atomic_load((const ull*)sp,     __ATOMIC_RELAXED, __HIP_MEMORY_SCOPE_SYSTEM);
                    ull v1 = __hip_atomic_load((const ull*)sp + 1, __ATOMIC_RELAXED, __HIP_MEMORY_SCOPE_SYSTEM);
                    ull* d = (ull*)(At + row * PITCH + c8 * 16);
                    d[0] = v0; d[1] = v1;
                }
            }
            __syncthreads();                  // (C) h staged

            // ---- MFMA K-loop (post-gate): L0 kt 8..23, L1 kt 0..31 ----
#pragma unroll
            for (int kt = (LAYER == 0 ? KTX : 0); kt < KT; ++kt) {
                s16x8 a = *(const s16x8*)(ap + kt * 64);
                acc0 = __builtin_amdgcn_mfma_f32_16x16x32_bf16(a, bfr0[kt], acc0, 0, 0, 0);
                acc1 = __builtin_amdgcn_mfma_f32_16x16x32_bf16(a, bfr1[kt], acc1, 0, 0, 0);
            }

            // ---- nonlinearity via shfl_xor(8,16); no LDS round trip ----
            const bool hi = (lm & 8) != 0;
            float hv[4];
#pragma unroll
            for (int r = 0; r < 4; ++r) {
                float a0 = acc0[r] + bv0;
                float a1 = acc1[r] + bv1;
                float a0x = __shfl_xor(a0, 8, 16);
                float a1x = __shfl_xor(a1, 8, 16);
                float iv = hi ? a0x : a0;
                float fv = hi ? a0  : a0x;
                float gv = hi ? a1x : a1;
                float ov = hi ? a1  : a1x;
                float cn = sigm(fv) * cst[r] + sigm(iv) * tanhc(gv);
                cst[r] = cn;
                hv[r] = sigm(ov) * tanhc(cn);
            }

            // ---- 8x4 register transpose -> packed 8-B h stores ----
            // Lane lm(<8) of quad lq ends with row lq*4+(lm>>1),
            // cols w*8+(lm&1)*4..+3.
            ull packed = 0;
#pragma unroll
            for (int r = 0; r < 4; ++r)
                packed |= ((ull)f2bf(hv[r])) << (16 * r);
            ull outp = 0;
            const int rp = (lm >> 1) & 3;
#pragma unroll
            for (int e = 0; e < 4; ++e) {
                ull got = __shfl(packed, (lm & 1) * 4 + e, 16);
                ull val = (got >> (16 * rp)) & 0xFFFFull;
                outp |= val << (16 * e);
            }
            if (lm < 8) {
                int brow = lq * 4 + (lm >> 1);
                size_t off = (size_t)(pw * 128 + g * 16 + brow) * 512
                           + rt * 32 + w * 8 + (lm & 1) * 4;
                __hip_atomic_store((ull*)(hself + off), outp,
                                   __ATOMIC_RELAXED, __HIP_MEMORY_SCOPE_SYSTEM);
            }
        }

        // ---- publish: syncthreads drains vmcnt(0) per wave, then tag ----
        __syncthreads();                      // (D)
        if (tid == 0)
            __hip_atomic_store(mytag, (unsigned)(s + 1),
                               __ATOMIC_RELAXED, __HIP_MEMORY_SCOPE_SYSTEM);
    }
}

__launch_bounds__(256, 1)
__global__ void k_lstm(const float* __restrict__ x,
                       const float* __restrict__ b0,
                       const float* __restrict__ b1,
                       const unsigned short* __restrict__ wsB0,
                       const unsigned short* __restrict__ wsB1,
                       unsigned short* hb0, unsigned short* hb1,
                       unsigned* tags) {
    __shared__ __align__(16) char Atile[16 * 2112];      // A tile, max pitch (L1)

    const int tid = threadIdx.x;
    const int g = blockIdx.x & 7, sub = blockIdx.x >> 3;
    const int layer = sub >> 4, rt = sub & 15;
    const int w = tid >> 6, lane = tid & 63;
    const int lm = lane & 15;

    unsigned* gtags = tags + (size_t)g * 32 * 32;        // 32 tags, 128-B spaced
    unsigned* mytag = gtags + (size_t)(layer * 16 + rt) * 32;

    const float* bias = layer ? b1 : b0;
    const int jsub = rt * 32 + w * 8 + (lm & 7);
    const int G0 = (lm & 8) ? 1 : 0;                     // acc0: i | f
    const float bv0 = bias[G0 * 512 + jsub];
    const float bv1 = bias[(G0 + 2) * 512 + jsub];       // acc1: g | o

    if (layer == 0)
        run_layer<0, 24>(x, wsB0, hb0, hb0, gtags, mytag, bv0, bv1,
                         g, rt, w, lane, tid, Atile);
    else
        run_layer<1, 32>(x, wsB1, hb0, hb1, gtags, mytag, bv0, bv1,
                         g, rt, w, lane, tid, Atile);
}

// ---------------------------------------------------------------------------
// FC epilogue: out[i] = dot(hn[i], fc_w) + fc_b, hn = [h0(511); h1(511)]
// h0(511) was written at epoch 511 -> slot 1; h1(511) at epoch 512 -> slot 0.
// ---------------------------------------------------------------------------
__global__ void k_fc(const unsigned short* __restrict__ hb0,
                     const unsigned short* __restrict__ hb1,
                     const float* __restrict__ fcw, const float* __restrict__ fcb,
                     float* __restrict__ out) {
    int i = blockIdx.x, lane = threadIdx.x;
    const unsigned short* hrow = (i < 128) ? (hb0 + (size_t)(128 + i) * 512)      // slot 1
                                           : (hb1 + (size_t)(i - 128) * 512);     // slot 0
    float ssum = 0.f;
    int j0 = lane * 8;
#pragma unroll
    for (int e = 0; e < 8; ++e) ssum += bf2f(hrow[j0 + e]) * fcw[j0 + e];
#pragma unroll
    for (int off2 = 32; off2 > 0; off2 >>= 1) ssum += __shfl_down(ssum, off2);
    if (lane == 0) out[i] = ssum + fcb[0];
}

// ---------------------------------------------------------------------------
extern "C" void kernel_launch(void* const* d_in, const int* in_sizes, int n_in,
                              void* d_out, int out_size, void* d_ws, size_t ws_size,
                              hipStream_t stream) {
    const float* x    = (const float*)d_in[0];
    const float* wih0 = (const float*)d_in[1];
    const float* whh0 = (const float*)d_in[2];
    const float* b0   = (const float*)d_in[3];
    const float* wih1 = (const float*)d_in[4];
    const float* whh1 = (const float*)d_in[5];
    const float* b1   = (const float*)d_in[6];
    const float* fcw  = (const float*)d_in[7];
    const float* fcb  = (const float*)d_in[8];

    unsigned short* wsB0 = (unsigned short*)d_ws;
    unsigned short* wsB1 = wsB0 + WSB1_OFF;
    unsigned short* hb0  = wsB0 + HB0_OFF;
    unsigned short* hb1  = wsB0 + HB1_OFF;
    unsigned* tags = (unsigned*)((char*)d_ws + TAGS_BYTE_OFF);
    float* out = (float*)d_out;

    k_prep<<<dim3(1857), dim3(256), 0, stream>>>(wih0, whh0, wih1, whh1,
                                                 wsB0, wsB1, hb0, hb1, tags);

    k_lstm<<<dim3(256), dim3(256), 0, stream>>>(x, b0, b1, wsB0, wsB1, hb0, hb1, tags);

    k_fc<<<dim3(256), dim3(64), 0, stream>>>(hb0, hb1, fcw, fcb, out);
}

// Round 5
// 2656.286 us; speedup vs baseline: 1.0749x; 1.0749x over previous
//
#include <hip/hip_runtime.h>
#include <stdint.h>

// ---------------------------------------------------------------------------
// BasicLSTM on MI355X — persistent pipelined 2-layer LSTM, round 10.
//
// Structure: 256 WGs x 256 threads, 1 block/CU (launch_bounds 256,1).
// 8 batch groups x 16 rows; per group 32 WGs (2 layers x 16 col-slices).
// Weights live in registers (MFMA B-frags) for all 513 epochs.
//
// ROUND-10: split the monolithic 32-tag gate by TRUE dependency set.
// Round-9's null result (dead neutral on moving L0 work pre-gate) proved
// the period is set by the joint gate + the slowest member's (L1's)
// post-gate chain, not by L0's path. Changes (comm primitives, tag
// semantics, publish, slots: identical to verified round 5/9):
//  * L0: flow-gate on 16 L0 tags before h-staging; anti-gate (L1 readers
//    of the h0 slot) moved to JUST BEFORE the h-store — overlaps all of
//    L0's staging/MFMA/nonlinearity.
//  * L1: gate on own 16 L1 tags -> stage h1 -> h1-half MFMAs (kt 16..31);
//    then gate on 16 L0 tags -> stage y0 -> y0-half MFMAs (kt 0..15).
//    L0's publish arrives latest, so h1 work overlaps that wait and the
//    post-L0-detect chain shrinks ~3500 -> ~2200 cy.
// Deadlock audit: every wait references only epoch s-1 completions
// (L0 flow L0>=s; L0 anti L1>=s; L1 own L1>=s; L1 cross L0>=s — all
// published at end of epoch s-1). Induction from tags=0; no intra-epoch
// circular waits; barriers WG-uniform. +1 barrier/epoch per layer.
// ---------------------------------------------------------------------------

using s16x8 = __attribute__((ext_vector_type(8))) short;   // 8 bf16 = 4 VGPRs
using f32x4 = __attribute__((ext_vector_type(4))) float;
typedef unsigned long long ull;

#define WSB1_OFF 1572864     // L0 frags: 16*8*24*512 = 1572864 ushorts
#define HB0_OFF  3670016     // h0 slots: 2*128*512 = 131072
#define HB1_OFF  3801088     // h1 slots: 131072 (end 3932160)
#define TAGS_BYTE_OFF 7864320  // 256 tags * 128 B = 32 KB

__device__ __forceinline__ float bf2f(unsigned short u) {
    unsigned v = ((unsigned)u) << 16;
    return __builtin_bit_cast(float, v);
}
__device__ __forceinline__ unsigned short f2bf(float f) {
    unsigned x = __builtin_bit_cast(unsigned, f);
    x += 0x7FFFu + ((x >> 16) & 1u);          // RNE (finite values only)
    return (unsigned short)(x >> 16);
}
__device__ __forceinline__ float sigm(float x) { return 1.f / (1.f + __expf(-x)); }
__device__ __forceinline__ float tanhc(float x) {
    x = fminf(15.f, fmaxf(-15.f, x));
    float e = __expf(-2.f * x);
    return (1.f - e) / (1.f + e);
}
__device__ __forceinline__ unsigned tagld(const unsigned* p) {
    return __hip_atomic_load(p, __ATOMIC_RELAXED, __HIP_MEMORY_SCOPE_SYSTEM);
}

// ---------------------------------------------------------------------------
// Prep: weights fp32 -> bf16 MFMA B-frags in packed-gate layout; zero the
// h slots that epoch-0/1 consumers read as "h(-1)"; zero tags.
// Packed layout: slice rt, wave w owns hidden cols j = w*8..w*8+7;
//   tile (w,0) cols = [i(j0..7) | f(j0..7)], tile (w,1) = [g(j0..7) | o(j0..7)].
// ---------------------------------------------------------------------------
__device__ __forceinline__ void store_frag(unsigned short* dst, int n, int kc, int KT,
                                           const float* src) {
    s16x8 v;
#pragma unroll
    for (int e = 0; e < 8; ++e) v[e] = (short)f2bf(src[e]);
    int gate = n >> 9, hid = n & 511;
    int rt = hid >> 5;
    int w  = (hid >> 3) & 3;
    int t  = gate >> 1;
    int lo = (gate & 1) * 8 + (hid & 7);
    int tileIdx = w * 2 + t;
    int kt = kc >> 2, q = kc & 3;
    int lane = q * 16 + lo;
    size_t off = ((((size_t)rt * 8 + tileIdx) * KT + kt) * 64 + lane) * 8;
    *(s16x8*)(dst + off) = v;
}

__global__ void k_prep(const float* __restrict__ wih0, const float* __restrict__ whh0,
                       const float* __restrict__ wih1, const float* __restrict__ whh1,
                       unsigned short* __restrict__ wsB0, unsigned short* __restrict__ wsB1,
                       unsigned short* __restrict__ hb0, unsigned short* __restrict__ hb1,
                       unsigned* __restrict__ tags) {
    int idx = blockIdx.x * 256 + threadIdx.x;
    if (idx < 196608) {                       // L0: 2048 rows x 96 k-chunks
        int n = idx / 96, kc = idx - n * 96;
        int k = kc * 8;
        const float* src = (k < 256) ? (wih0 + (size_t)n * 256 + k)
                                     : (whh0 + (size_t)n * 512 + (k - 256));
        store_frag(wsB0, n, kc, 24, src);
    } else if (idx < 458752) {                // L1: 2048 rows x 128 k-chunks
        int j = idx - 196608;
        int n = j >> 7, kc = j & 127;
        int k = kc * 8;
        const float* src = (k < 512) ? (wih1 + (size_t)n * 512 + k)
                                     : (whh1 + (size_t)n * 512 + (k - 512));
        store_frag(wsB1, n, kc, 32, src);
    } else {
        int z = idx - 458752;
        if (z < 8192) {                       // zero hb0 slot 1 (h0(-1))
            ull* p = (ull*)(hb0 + 65536 + (size_t)z * 8);
            p[0] = 0ull; p[1] = 0ull;
        } else if (z < 16384) {               // zero hb1 slot 0 (h1(-1))
            ull* p = (ull*)(hb1 + (size_t)(z - 8192) * 8);
            p[0] = 0ull; p[1] = 0ull;
        } else if (z < 16640) {               // zero 256 tag words (128-B spaced)
            tags[(size_t)(z - 16384) * 32] = 0u;
        }
    }
}

// ---------------------------------------------------------------------------
// Persistent LSTM kernel
// ---------------------------------------------------------------------------
template <int LAYER, int KT>
__device__ __forceinline__ void run_layer(const float* __restrict__ x,
                                          const unsigned short* __restrict__ wsB,
                                          unsigned short* hsrc0,   // L0: hb0 ; L1: hb0 (y0)
                                          unsigned short* hself,   // write target (hb0/hb1)
                                          unsigned* tags,          // group tag base (32 tags)
                                          unsigned* mytag,
                                          float bv0, float bv1,
                                          int g, int rt, int w, int lane, int tid,
                                          char* At) {
    constexpr int PITCH = (LAYER == 0) ? 1600 : 2112;   // bytes/row, ==64 mod 128
    constexpr int KTX   = 8;                            // L0 x-half KT count
    constexpr int KTY   = 16;                           // L1 y0-half KT count
    const int lm = lane & 15, lq = lane >> 4;

    // --- weight fragments into registers/AGPRs (live across all epochs) ---
    s16x8 bfr0[KT], bfr1[KT];
    {
        const unsigned short* base = wsB + (((size_t)rt * 8 + 2 * w) * KT) * 512;
#pragma unroll
        for (int kt = 0; kt < KT; ++kt) {
            bfr0[kt] = *(const s16x8*)(base + ((size_t)kt * 64 + lane) * 8);
            bfr1[kt] = *(const s16x8*)(base + (((size_t)KT + kt) * 64 + lane) * 8);
        }
    }

    float cst[4] = {0.f, 0.f, 0.f, 0.f};      // cell state: (b=lq*4+r, j=w*8+(lm&7))

    // --- x prefetch state (L0 only): x(0) preloaded before the loop ---
    f32x4 xa[2], xb[2];
    int xrow[2], xch[2];
    if (LAYER == 0) {
#pragma unroll
        for (int i = 0; i < 2; ++i) {
            int task = tid + i * 256;         // 16 rows x 32 chunks (8 fp32 each)
            xrow[i] = task >> 5; xch[i] = task & 31;
            const float* src = x + ((size_t)(g * 16 + xrow[i]) * 512) * 256 + xch[i] * 8;
            xa[i] = *(const f32x4*)(src);
            xb[i] = *(const f32x4*)(src + 4);
        }
    }

#pragma unroll 1
    for (int s = 0; s <= 512; ++s) {
        const bool active = LAYER ? (s >= 1) : (s < 512);
        const int pr = (s + 1) & 1;           // read slot
        const int pw = s & 1;                 // write slot

        if (active) {
            f32x4 acc0 = {0.f, 0.f, 0.f, 0.f}, acc1 = {0.f, 0.f, 0.f, 0.f};
            const char* ap = At + lm * PITCH + lq * 16;

            if (LAYER == 0) {
                // ---- pre-gate: stage x(s), prefetch x(s+1) ----
#pragma unroll
                for (int i = 0; i < 2; ++i) {
                    s16x8 v;
#pragma unroll
                    for (int e = 0; e < 4; ++e) { v[e] = (short)f2bf(xa[i][e]); v[4 + e] = (short)f2bf(xb[i][e]); }
                    *(s16x8*)(At + xrow[i] * PITCH + xch[i] * 16) = v;
                }
                if (s + 1 < 512) {
#pragma unroll
                    for (int i = 0; i < 2; ++i) {
                        const float* src = x + ((size_t)(g * 16 + xrow[i]) * 512 + (s + 1)) * 256 + xch[i] * 8;
                        xa[i] = *(const f32x4*)(src);
                        xb[i] = *(const f32x4*)(src + 4);
                    }
                }
                __syncthreads();              // (A) x staged

                // ---- x-half MFMAs (no inter-WG dependency) ----
#pragma unroll
                for (int kt = 0; kt < KTX; ++kt) {
                    s16x8 a = *(const s16x8*)(ap + kt * 64);
                    acc0 = __builtin_amdgcn_mfma_f32_16x16x32_bf16(a, bfr0[kt], acc0, 0, 0, 0);
                    acc1 = __builtin_amdgcn_mfma_f32_16x16x32_bf16(a, bfr1[kt], acc1, 0, 0, 0);
                }

                // ---- flow-gate: 16 L0 tags >= s (peers' h0(s-1) ready) ----
                if (tid < 16) {
                    unsigned* tp = tags + (size_t)tid * 32;
                    while (tagld(tp) < (unsigned)s) __builtin_amdgcn_s_sleep(1);
                }
                __syncthreads();              // (B)

                // ---- stage h0(s-1): 16 rows x 64 chunks (16 B) ----
#pragma unroll
                for (int i = 0; i < 4; ++i) {
                    int task = tid + i * 256;
                    int row = task >> 6, c8 = task & 63;
                    const ull* sp = (const ull*)(hsrc0 + (size_t)(pr * 128 + g * 16 + row) * 512 + c8 * 8);
                    ull v0 = __hip_atomic_load(sp,     __ATOMIC_RELAXED, __HIP_MEMORY_SCOPE_SYSTEM);
                    ull v1 = __hip_atomic_load(sp + 1, __ATOMIC_RELAXED, __HIP_MEMORY_SCOPE_SYSTEM);
                    ull* d = (ull*)(At + row * PITCH + 512 + c8 * 16);
                    d[0] = v0; d[1] = v1;
                }
                __syncthreads();              // (C) h staged

                // ---- h-half MFMAs (kt 8..23) ----
#pragma unroll
                for (int kt = KTX; kt < KT; ++kt) {
                    s16x8 a = *(const s16x8*)(ap + kt * 64);
                    acc0 = __builtin_amdgcn_mfma_f32_16x16x32_bf16(a, bfr0[kt], acc0, 0, 0, 0);
                    acc1 = __builtin_amdgcn_mfma_f32_16x16x32_bf16(a, bfr1[kt], acc1, 0, 0, 0);
                }
            } else {
                // ---- own-gate: 16 L1 tags >= s (h1(s-1) ready; also anti) ----
                if (tid < 16) {
                    unsigned* tp = tags + (size_t)(16 + tid) * 32;
                    while (tagld(tp) < (unsigned)s) __builtin_amdgcn_s_sleep(1);
                }
                __syncthreads();              // (B1)

                // ---- stage h1(s-1): 16 rows x 64 chunks -> At bytes 1024+ ----
#pragma unroll
                for (int i = 0; i < 4; ++i) {
                    int task = tid + i * 256;
                    int row = task >> 6, c8 = task & 63;
                    const ull* sp = (const ull*)(hself + (size_t)(pr * 128 + g * 16 + row) * 512 + c8 * 8);
                    ull v0 = __hip_atomic_load(sp,     __ATOMIC_RELAXED, __HIP_MEMORY_SCOPE_SYSTEM);
                    ull v1 = __hip_atomic_load(sp + 1, __ATOMIC_RELAXED, __HIP_MEMORY_SCOPE_SYSTEM);
                    ull* d = (ull*)(At + row * PITCH + 1024 + c8 * 16);
                    d[0] = v0; d[1] = v1;
                }
                __syncthreads();              // (C1) h1 staged

                // ---- h1-half MFMAs (kt 16..31) — overlaps the wait for L0 ----
#pragma unroll
                for (int kt = KTY; kt < KT; ++kt) {
                    s16x8 a = *(const s16x8*)(ap + kt * 64);
                    acc0 = __builtin_amdgcn_mfma_f32_16x16x32_bf16(a, bfr0[kt], acc0, 0, 0, 0);
                    acc1 = __builtin_amdgcn_mfma_f32_16x16x32_bf16(a, bfr1[kt], acc1, 0, 0, 0);
                }

                // ---- cross-gate: 16 L0 tags >= s (y0(s-1) ready) ----
                if (tid < 16) {
                    unsigned* tp = tags + (size_t)tid * 32;
                    while (tagld(tp) < (unsigned)s) __builtin_amdgcn_s_sleep(1);
                }
                __syncthreads();              // (B2)

                // ---- stage y0(s-1): 16 rows x 64 chunks -> At bytes 0..1023 ----
#pragma unroll
                for (int i = 0; i < 4; ++i) {
                    int task = tid + i * 256;
                    int row = task >> 6, c8 = task & 63;
                    const ull* sp = (const ull*)(hsrc0 + (size_t)(pr * 128 + g * 16 + row) * 512 + c8 * 8);
                    ull v0 = __hip_atomic_load(sp,     __ATOMIC_RELAXED, __HIP_MEMORY_SCOPE_SYSTEM);
                    ull v1 = __hip_atomic_load(sp + 1, __ATOMIC_RELAXED, __HIP_MEMORY_SCOPE_SYSTEM);
                    ull* d = (ull*)(At + row * PITCH + c8 * 16);
                    d[0] = v0; d[1] = v1;
                }
                __syncthreads();              // (C2) y0 staged

                // ---- y0-half MFMAs (kt 0..15) ----
#pragma unroll
                for (int kt = 0; kt < KTY; ++kt) {
                    s16x8 a = *(const s16x8*)(ap + kt * 64);
                    acc0 = __builtin_amdgcn_mfma_f32_16x16x32_bf16(a, bfr0[kt], acc0, 0, 0, 0);
                    acc1 = __builtin_amdgcn_mfma_f32_16x16x32_bf16(a, bfr1[kt], acc1, 0, 0, 0);
                }
            }

            // ---- nonlinearity via shfl_xor(8,16); no LDS round trip ----
            const bool hi = (lm & 8) != 0;
            float hv[4];
#pragma unroll
            for (int r = 0; r < 4; ++r) {
                float a0 = acc0[r] + bv0;
                float a1 = acc1[r] + bv1;
                float a0x = __shfl_xor(a0, 8, 16);
                float a1x = __shfl_xor(a1, 8, 16);
                float iv = hi ? a0x : a0;
                float fv = hi ? a0  : a0x;
                float gv = hi ? a1x : a1;
                float ov = hi ? a1  : a1x;
                float cn = sigm(fv) * cst[r] + sigm(iv) * tanhc(gv);
                cst[r] = cn;
                hv[r] = sigm(ov) * tanhc(cn);
            }

            // ---- L0 anti-gate (late): L1 readers of h0 slot pw done ----
            if (LAYER == 0) {
                if (tid < 16) {
                    unsigned* tp = tags + (size_t)(16 + tid) * 32;
                    while (tagld(tp) < (unsigned)s) __builtin_amdgcn_s_sleep(1);
                }
                __syncthreads();              // (E)
            }

            // ---- 8x4 register transpose -> packed 8-B h stores ----
            // Lane lm(<8) of quad lq ends with row lq*4+(lm>>1),
            // cols w*8+(lm&1)*4..+3.
            ull packed = 0;
#pragma unroll
            for (int r = 0; r < 4; ++r)
                packed |= ((ull)f2bf(hv[r])) << (16 * r);
            ull outp = 0;
            const int rp = (lm >> 1) & 3;
#pragma unroll
            for (int e = 0; e < 4; ++e) {
                ull got = __shfl(packed, (lm & 1) * 4 + e, 16);
                ull val = (got >> (16 * rp)) & 0xFFFFull;
                outp |= val << (16 * e);
            }
            if (lm < 8) {
                int brow = lq * 4 + (lm >> 1);
                size_t off = (size_t)(pw * 128 + g * 16 + brow) * 512
                           + rt * 32 + w * 8 + (lm & 1) * 4;
                __hip_atomic_store((ull*)(hself + off), outp,
                                   __ATOMIC_RELAXED, __HIP_MEMORY_SCOPE_SYSTEM);
            }
        }

        // ---- publish: syncthreads drains vmcnt(0) per wave, then tag ----
        __syncthreads();                      // (D)
        if (tid == 0)
            __hip_atomic_store(mytag, (unsigned)(s + 1),
                               __ATOMIC_RELAXED, __HIP_MEMORY_SCOPE_SYSTEM);
    }
}

__launch_bounds__(256, 1)
__global__ void k_lstm(const float* __restrict__ x,
                       const float* __restrict__ b0,
                       const float* __restrict__ b1,
                       const unsigned short* __restrict__ wsB0,
                       const unsigned short* __restrict__ wsB1,
                       unsigned short* hb0, unsigned short* hb1,
                       unsigned* tags) {
    __shared__ __align__(16) char Atile[16 * 2112];      // A tile, max pitch (L1)

    const int tid = threadIdx.x;
    const int g = blockIdx.x & 7, sub = blockIdx.x >> 3;
    const int layer = sub >> 4, rt = sub & 15;
    const int w = tid >> 6, lane = tid & 63;
    const int lm = lane & 15;

    unsigned* gtags = tags + (size_t)g * 32 * 32;        // 32 tags, 128-B spaced
    unsigned* mytag = gtags + (size_t)(layer * 16 + rt) * 32;

    const float* bias = layer ? b1 : b0;
    const int jsub = rt * 32 + w * 8 + (lm & 7);
    const int G0 = (lm & 8) ? 1 : 0;                     // acc0: i | f
    const float bv0 = bias[G0 * 512 + jsub];
    const float bv1 = bias[(G0 + 2) * 512 + jsub];       // acc1: g | o

    if (layer == 0)
        run_layer<0, 24>(x, wsB0, hb0, hb0, gtags, mytag, bv0, bv1,
                         g, rt, w, lane, tid, Atile);
    else
        run_layer<1, 32>(x, wsB1, hb0, hb1, gtags, mytag, bv0, bv1,
                         g, rt, w, lane, tid, Atile);
}

// ---------------------------------------------------------------------------
// FC epilogue: out[i] = dot(hn[i], fc_w) + fc_b, hn = [h0(511); h1(511)]
// h0(511) was written at epoch 511 -> slot 1; h1(511) at epoch 512 -> slot 0.
// ---------------------------------------------------------------------------
__global__ void k_fc(const unsigned short* __restrict__ hb0,
                     const unsigned short* __restrict__ hb1,
                     const float* __restrict__ fcw, const float* __restrict__ fcb,
                     float* __restrict__ out) {
    int i = blockIdx.x, lane = threadIdx.x;
    const unsigned short* hrow = (i < 128) ? (hb0 + (size_t)(128 + i) * 512)      // slot 1
                                           : (hb1 + (size_t)(i - 128) * 512);     // slot 0
    float ssum = 0.f;
    int j0 = lane * 8;
#pragma unroll
    for (int e = 0; e < 8; ++e) ssum += bf2f(hrow[j0 + e]) * fcw[j0 + e];
#pragma unroll
    for (int off2 = 32; off2 > 0; off2 >>= 1) ssum += __shfl_down(ssum, off2);
    if (lane == 0) out[i] = ssum + fcb[0];
}

// ---------------------------------------------------------------------------
extern "C" void kernel_launch(void* const* d_in, const int* in_sizes, int n_in,
                              void* d_out, int out_size, void* d_ws, size_t ws_size,
                              hipStream_t stream) {
    const float* x    = (const float*)d_in[0];
    const float* wih0 = (const float*)d_in[1];
    const float* whh0 = (const float*)d_in[2];
    const float* b0   = (const float*)d_in[3];
    const float* wih1 = (const float*)d_in[4];
    const float* whh1 = (const float*)d_in[5];
    const float* b1   = (const float*)d_in[6];
    const float* fcw  = (const float*)d_in[7];
    const float* fcb  = (const float*)d_in[8];

    unsigned short* wsB0 = (unsigned short*)d_ws;
    unsigned short* wsB1 = wsB0 + WSB1_OFF;
    unsigned short* hb0  = wsB0 + HB0_OFF;
    unsigned short* hb1  = wsB0 + HB1_OFF;
    unsigned* tags = (unsigned*)((char*)d_ws + TAGS_BYTE_OFF);
    float* out = (float*)d_out;

    k_prep<<<dim3(1857), dim3(256), 0, stream>>>(wih0, whh0, wih1, whh1,
                                                 wsB0, wsB1, hb0, hb1, tags);

    k_lstm<<<dim3(256), dim3(256), 0, stream>>>(x, b0, b1, wsB0, wsB1, hb0, hb1, tags);

    k_fc<<<dim3(256), dim3(64), 0, stream>>>(hb0, hb1, fcw, fcb, out);
}